// Round 7
// baseline (3079.730 us; speedup 1.0000x reference)
//
#include <hip/hip_runtime.h>
#include <stdint.h>

#define B_ 64
#define T_ 4096
#define C_ 32

typedef unsigned int uint32;
typedef unsigned short ushort16;
typedef unsigned int uint32x2 __attribute__((ext_vector_type(2)));

__device__ __forceinline__ float bf2f(ushort16 u) {
    return __uint_as_float(((uint32)u) << 16);
}
__device__ __forceinline__ uint32 f2bf_bits(float f) {  // round-to-nearest-even bf16
    uint32 u = __float_as_uint(f);
    uint32 r = u + 0x7fffu + ((u >> 16) & 1u);
    return r >> 16;
}
__device__ __forceinline__ void unpack2(uint32 u, float& f0, float& f1) {
    f0 = __uint_as_float(u << 16);
    f1 = __uint_as_float(u & 0xffff0000u);
}
__device__ __forceinline__ float fast_sigmoid(float x) {
    float e = __builtin_amdgcn_exp2f(x * -1.442695040889f);
    return __builtin_amdgcn_rcpf(1.0f + e);
}

// half-swap across the two 32-lane halves; returns (z_bcast, n_bcast) given
// v = z in lanes 0-31, n in lanes 32-63.
__device__ __forceinline__ void half_swap(uint32 vb, uint32& zb, uint32& nb) {
#if __has_builtin(__builtin_amdgcn_permlane32_swap)
    uint32x2 sw = __builtin_amdgcn_permlane32_swap(vb, vb, false, false);
    zb = sw.x; nb = sw.y;
#else
    uint32 a = vb, b = vb;
    asm("v_permlane32_swap_b32 %0, %1" : "+v"(a), "+v"(b));
    zb = a; nb = b;
#endif
}

// ---------------------------------------------------------------------------
// Kernel A: conv_in + down1-5 + feat1-5 + gi1 (input gates for gru1, bf16)
// ---------------------------------------------------------------------------
__global__ __launch_bounds__(256) void kA(
    const float* __restrict__ x, const float* __restrict__ w_in, const float* __restrict__ b_in,
    const float* __restrict__ W32, const float* __restrict__ B32,
    const float* __restrict__ wih1, const float* __restrict__ bih1, const float* __restrict__ bhh1,
    ushort16* __restrict__ gi1)
{
    const int row = blockIdx.x * 256 + threadIdx.x;  // 0 .. B*T-1
    const float4* xr = (const float4*)(x + (size_t)row * 8);
    float4 x0 = xr[0], x1 = xr[1];
    float xv[8] = {x0.x, x0.y, x0.z, x0.w, x1.x, x1.y, x1.z, x1.w};

    float h[C_], hn[C_];
#pragma unroll
    for (int o = 0; o < C_; o++) {
        float a = b_in[o];
#pragma unroll
        for (int j = 0; j < 8; j++) a = fmaf(xv[j], w_in[o * 8 + j], a);
        h[o] = fmaxf(a, 0.0f);
    }
#pragma unroll 1
    for (int L = 0; L < 10; L++) {
        const float* W = W32 + L * C_ * C_;
        const float* bb = B32 + L * C_;
#pragma unroll
        for (int o = 0; o < C_; o++) {
            float a = bb[o];
#pragma unroll
            for (int j = 0; j < C_; j++) a = fmaf(h[j], W[o * C_ + j], a);
            hn[o] = fmaxf(a, 0.0f);
        }
#pragma unroll
        for (int o = 0; o < C_; o++) h[o] = hn[o];
    }
    // gi1: gates 32..95 only (r-gate is dead). Fold bih+bhh.
    uint4* dst = (uint4*)(gi1 + (size_t)row * 64);
#pragma unroll
    for (int k = 0; k < 8; k++) {
        uint32 wbuf[4];
#pragma unroll
        for (int p = 0; p < 4; p++) {
            int o0 = k * 8 + p * 2;
            float a0 = bih1[32 + o0] + bhh1[32 + o0];
            float a1 = bih1[33 + o0] + bhh1[33 + o0];
#pragma unroll
            for (int j = 0; j < C_; j++) {
                a0 = fmaf(h[j], wih1[(32 + o0) * C_ + j], a0);
                a1 = fmaf(h[j], wih1[(33 + o0) * C_ + j], a1);
            }
            wbuf[p] = f2bf_bits(a0) | (f2bf_bits(a1) << 16);
        }
        dst[k] = make_uint4(wbuf[0], wbuf[1], wbuf[2], wbuf[3]);
    }
}

// ---------------------------------------------------------------------------
// GRU scan: one wave per sequence. Lanes 0-31 compute z-gates, lanes 32-63
// compute n-gates. h replicated across both halves (h_mine = h[lane&31]).
// Critical path per step:
//   readlane(h)+fma interleaved (4 acc chains) -> exp2/rcp -> permlane32_swap
//   -> h update. log2e gate scale folded into w and prefetched gi.
// ---------------------------------------------------------------------------
__global__ __launch_bounds__(64) void kGru(
    const ushort16* __restrict__ gi_f, const ushort16* __restrict__ gi_r,
    const float* __restrict__ whh_f, const float* __restrict__ whh_r,
    ushort16* __restrict__ out, int outStride, int col_f, int col_r)
{
    const int blk = blockIdx.x;
    const bool rev = blk >= 64;
    const int b = blk & 63;
    const int lane = threadIdx.x;
    const bool isZ = lane < 32;

    const ushort16* gi = rev ? gi_r : gi_f;
    const float* whh = rev ? whh_r : whh_f;
    const int colbase = rev ? col_r : col_f;

    // z: sigmoid(x) = rcp(1+2^(-x*log2e));  n: tanh(x) = 2*rcp(1+2^(-2x*log2e))-1
    const float cs = isZ ? -1.442695040889f : -2.885390081777f;
    const float cm = isZ ? 1.0f : 2.0f;
    const float ca = isZ ? 0.0f : -1.0f;

    // recurrent weights for this lane's gate, pre-scaled by cs
    float w[32];
    const float4* wr = (const float4*)(whh + (32 + lane) * 32);
#pragma unroll
    for (int k = 0; k < 8; k++) {
        float4 q = wr[k];
        w[4 * k + 0] = q.x * cs; w[4 * k + 1] = q.y * cs;
        w[4 * k + 2] = q.z * cs; w[4 * k + 3] = q.w * cs;
    }

    uint32 hb = 0;        // bits of h[lane&31], valid in ALL lanes
    float h_mine = 0.0f;  // h[lane&31], maintained in all lanes

    const ushort16* gp = gi + (size_t)b * T_ * 64 + lane;

    float gbuf[8];  // 8-deep prefetch of gi, pre-scaled by cs (off critical path)
#pragma unroll
    for (int u = 0; u < 8; u++) {
        int t = rev ? (T_ - 1 - u) : u;
        gbuf[u] = bf2f(gp[(size_t)t * 64]) * cs;
    }

    for (int s0 = 0; s0 < T_; s0 += 8) {
#pragma unroll
        for (int u = 0; u < 8; u++) {
            const int s = s0 + u;
            float a0 = gbuf[u], a1 = 0.f, a2 = 0.f, a3 = 0.f;
            // prefetch step s+8 (clamped; value unused past the end)
            int sp = s + 8; if (sp > T_ - 1) sp = T_ - 1;
            int tp = rev ? (T_ - 1 - sp) : sp;
            gbuf[u] = bf2f(gp[(size_t)tp * 64]) * cs;

            // dot(whh_row*cs, h): readlane broadcast fused into 4 fma chains
#pragma unroll
            for (int j = 0; j < 8; j++) {
                a0 = fmaf(__uint_as_float(__builtin_amdgcn_readlane(hb, j)),      w[j],      a0);
                a1 = fmaf(__uint_as_float(__builtin_amdgcn_readlane(hb, j + 8)),  w[j + 8],  a1);
                a2 = fmaf(__uint_as_float(__builtin_amdgcn_readlane(hb, j + 16)), w[j + 16], a2);
                a3 = fmaf(__uint_as_float(__builtin_amdgcn_readlane(hb, j + 24)), w[j + 24], a3);
            }
            float gs = (a0 + a1) + (a2 + a3);       // = cs * (gi + whh@h)

            float e = __builtin_amdgcn_exp2f(gs);
            float r = __builtin_amdgcn_rcpf(1.0f + e);
            float v = fmaf(cm, r, ca);              // z (lanes<32) or n (lanes>=32)

            // half-swap via VALU permlane (no LDS round-trip)
            uint32 zb, nb;
            half_swap(__float_as_uint(v), zb, nb);
            float z_ = __uint_as_float(zb);
            float n_ = __uint_as_float(nb);

            float hnv = fmaf(z_, h_mine - n_, n_);  // (1-z)*n + z*h
            h_mine = hnv;
            hb = __float_as_uint(hnv);

            int t = rev ? (T_ - 1 - s) : s;
            if (lane < 32)
                out[((size_t)b * T_ + t) * outStride + colbase + lane] = (ushort16)f2bf_bits(hnv);
        }
    }
}

// ---------------------------------------------------------------------------
// Kernel C: dec1-3 + gi2 forward + gi2 reverse
// ---------------------------------------------------------------------------
__global__ __launch_bounds__(256) void kC(
    const ushort16* __restrict__ ys1,
    const float* __restrict__ W32, const float* __restrict__ B32,
    const float* __restrict__ wih2, const float* __restrict__ bih2, const float* __restrict__ bhh2,
    const float* __restrict__ wih2r, const float* __restrict__ bih2r, const float* __restrict__ bhh2r,
    ushort16* __restrict__ gi2f, ushort16* __restrict__ gi2r)
{
    const int row = blockIdx.x * 256 + threadIdx.x;
    float h[C_], hn[C_];
    const uint4* src = (const uint4*)(ys1 + (size_t)row * 32);
#pragma unroll
    for (int k = 0; k < 4; k++) {
        uint4 v = src[k];
        unpack2(v.x, h[8 * k + 0], h[8 * k + 1]);
        unpack2(v.y, h[8 * k + 2], h[8 * k + 3]);
        unpack2(v.z, h[8 * k + 4], h[8 * k + 5]);
        unpack2(v.w, h[8 * k + 6], h[8 * k + 7]);
    }
#pragma unroll 1
    for (int L = 10; L < 13; L++) {
        const float* W = W32 + L * C_ * C_;
        const float* bb = B32 + L * C_;
#pragma unroll
        for (int o = 0; o < C_; o++) {
            float a = bb[o];
#pragma unroll
            for (int j = 0; j < C_; j++) a = fmaf(h[j], W[o * C_ + j], a);
            hn[o] = fmaxf(a, 0.0f);
        }
#pragma unroll
        for (int o = 0; o < C_; o++) h[o] = hn[o];
    }
#pragma unroll 1
    for (int d = 0; d < 2; d++) {
        const float* wih = d ? wih2r : wih2;
        const float* bi = d ? bih2r : bih2;
        const float* bh = d ? bhh2r : bhh2;
        uint4* dst = (uint4*)((d ? gi2r : gi2f) + (size_t)row * 64);
#pragma unroll
        for (int k = 0; k < 8; k++) {
            uint32 wbuf[4];
#pragma unroll
            for (int p = 0; p < 4; p++) {
                int o0 = k * 8 + p * 2;
                float a0 = bi[32 + o0] + bh[32 + o0];
                float a1 = bi[33 + o0] + bh[33 + o0];
#pragma unroll
                for (int j = 0; j < C_; j++) {
                    a0 = fmaf(h[j], wih[(32 + o0) * C_ + j], a0);
                    a1 = fmaf(h[j], wih[(33 + o0) * C_ + j], a1);
                }
                wbuf[p] = f2bf_bits(a0) | (f2bf_bits(a1) << 16);
            }
            dst[k] = make_uint4(wbuf[0], wbuf[1], wbuf[2], wbuf[3]);
        }
    }
}

// ---------------------------------------------------------------------------
// Kernel E: up1 (64->32) + up2-5 + out head + sigmoid
// ---------------------------------------------------------------------------
__global__ __launch_bounds__(256) void kE(
    const ushort16* __restrict__ hcat,
    const float* __restrict__ w_up1, const float* __restrict__ b_up1,
    const float* __restrict__ W32, const float* __restrict__ B32,
    const float* __restrict__ w_out, const float* __restrict__ b_out,
    float* __restrict__ outp)
{
    const int row = blockIdx.x * 256 + threadIdx.x;
    float h64[64];
    const uint4* src = (const uint4*)(hcat + (size_t)row * 64);
#pragma unroll
    for (int k = 0; k < 8; k++) {
        uint4 v = src[k];
        unpack2(v.x, h64[8 * k + 0], h64[8 * k + 1]);
        unpack2(v.y, h64[8 * k + 2], h64[8 * k + 3]);
        unpack2(v.z, h64[8 * k + 4], h64[8 * k + 5]);
        unpack2(v.w, h64[8 * k + 6], h64[8 * k + 7]);
    }
    float h[C_], hn[C_];
#pragma unroll
    for (int o = 0; o < C_; o++) {
        float a = b_up1[o];
#pragma unroll
        for (int j = 0; j < 64; j++) a = fmaf(h64[j], w_up1[o * 64 + j], a);
        h[o] = fmaxf(a, 0.0f);
    }
#pragma unroll 1
    for (int L = 13; L < 17; L++) {
        const float* W = W32 + L * C_ * C_;
        const float* bb = B32 + L * C_;
#pragma unroll
        for (int o = 0; o < C_; o++) {
            float a = bb[o];
#pragma unroll
            for (int j = 0; j < C_; j++) a = fmaf(h[j], W[o * C_ + j], a);
            hn[o] = fmaxf(a, 0.0f);
        }
#pragma unroll
        for (int o = 0; o < C_; o++) h[o] = hn[o];
    }
    float r0 = b_out[0], r1 = b_out[1];
#pragma unroll
    for (int j = 0; j < C_; j++) {
        r0 = fmaf(h[j], w_out[j], r0);
        r1 = fmaf(h[j], w_out[32 + j], r1);
    }
    float2 res = make_float2(fast_sigmoid(r0), fast_sigmoid(r1));
    ((float2*)outp)[row] = res;
}

// ---------------------------------------------------------------------------
extern "C" void kernel_launch(void* const* d_in, const int* in_sizes, int n_in,
                              void* d_out, int out_size, void* d_ws, size_t ws_size,
                              hipStream_t stream) {
    const float* x     = (const float*)d_in[0];
    const float* w_in  = (const float*)d_in[1];
    const float* b_in  = (const float*)d_in[2];
    const float* W32   = (const float*)d_in[3];
    const float* B32   = (const float*)d_in[4];
    const float* w_up1 = (const float*)d_in[5];
    const float* b_up1 = (const float*)d_in[6];
    const float* w_out = (const float*)d_in[7];
    const float* b_out = (const float*)d_in[8];
    const float* wih1  = (const float*)d_in[9];
    const float* whh1  = (const float*)d_in[10];
    const float* bih1  = (const float*)d_in[11];
    const float* bhh1  = (const float*)d_in[12];
    const float* wih2  = (const float*)d_in[13];
    const float* whh2  = (const float*)d_in[14];
    const float* bih2  = (const float*)d_in[15];
    const float* bhh2  = (const float*)d_in[16];
    const float* wih2r = (const float*)d_in[17];
    const float* whh2r = (const float*)d_in[18];
    const float* bih2r = (const float*)d_in[19];
    const float* bhh2r = (const float*)d_in[20];

    const size_t NB = (size_t)B_ * T_;  // 262144 rows
    // Workspace layout (112 MB): gi2f aliases gi1 (dead after gru1).
    ushort16* gi1  = (ushort16*)d_ws;        // [NB][64] bf16 : 32 MB
    ushort16* gi2f = gi1;                    // aliases gi1
    ushort16* gi2r = gi1  + NB * 64;         // 32 MB
    ushort16* ys1  = gi2r + NB * 64;         // [NB][32] bf16 : 16 MB
    ushort16* hcat = ys1  + NB * 32;         // [NB][64] bf16 : 32 MB

    const int rowBlocks = (int)(NB / 256);   // 1024

    kA<<<rowBlocks, 256, 0, stream>>>(x, w_in, b_in, W32, B32, wih1, bih1, bhh1, gi1);
    kGru<<<64, 64, 0, stream>>>(gi1, gi1, whh1, whh1, ys1, 32, 0, 0);
    kC<<<rowBlocks, 256, 0, stream>>>(ys1, W32, B32, wih2, bih2, bhh2,
                                      wih2r, bih2r, bhh2r, gi2f, gi2r);
    kGru<<<128, 64, 0, stream>>>(gi2f, gi2r, whh2, whh2r, hcat, 64, 0, 32);
    kE<<<rowBlocks, 256, 0, stream>>>(hcat, w_up1, b_up1, W32, B32, w_out, b_out,
                                      (float*)d_out);
}

// Round 8
// 2206.428 us; speedup vs baseline: 1.3958x; 1.3958x over previous
//
#include <hip/hip_runtime.h>
#include <stdint.h>

#define B_ 64
#define T_ 4096
#define C_ 32

typedef unsigned int uint32;
typedef unsigned short ushort16;
typedef unsigned int uint32x2 __attribute__((ext_vector_type(2)));

__device__ __forceinline__ float bf2f(ushort16 u) {
    return __uint_as_float(((uint32)u) << 16);
}
__device__ __forceinline__ uint32 f2bf_bits(float f) {  // round-to-nearest-even bf16
    uint32 u = __float_as_uint(f);
    uint32 r = u + 0x7fffu + ((u >> 16) & 1u);
    return r >> 16;
}
__device__ __forceinline__ void unpack2(uint32 u, float& f0, float& f1) {
    f0 = __uint_as_float(u << 16);
    f1 = __uint_as_float(u & 0xffff0000u);
}
__device__ __forceinline__ float fast_sigmoid(float x) {
    float e = __builtin_amdgcn_exp2f(x * -1.442695040889f);
    return __builtin_amdgcn_rcpf(1.0f + e);
}

// half-swap across the two 32-lane halves; given v = z in lanes 0-31, n in
// lanes 32-63, returns (z broadcast to all lanes, n broadcast to all lanes).
// Verified on HW in round 7 (passed, absmax 0.0).
__device__ __forceinline__ void half_swap(uint32 vb, uint32& zb, uint32& nb) {
#if __has_builtin(__builtin_amdgcn_permlane32_swap)
    uint32x2 sw = __builtin_amdgcn_permlane32_swap(vb, vb, false, false);
    zb = sw.x; nb = sw.y;
#else
    uint32 a = vb, b = vb;
    asm("v_permlane32_swap_b32 %0, %1" : "+v"(a), "+v"(b));
    zb = a; nb = b;
#endif
}

// ---------------------------------------------------------------------------
// Kernel A: conv_in + down1-5 + feat1-5 + gi1 (input gates for gru1, bf16)
// ---------------------------------------------------------------------------
__global__ __launch_bounds__(256) void kA(
    const float* __restrict__ x, const float* __restrict__ w_in, const float* __restrict__ b_in,
    const float* __restrict__ W32, const float* __restrict__ B32,
    const float* __restrict__ wih1, const float* __restrict__ bih1, const float* __restrict__ bhh1,
    ushort16* __restrict__ gi1)
{
    const int row = blockIdx.x * 256 + threadIdx.x;  // 0 .. B*T-1
    const float4* xr = (const float4*)(x + (size_t)row * 8);
    float4 x0 = xr[0], x1 = xr[1];
    float xv[8] = {x0.x, x0.y, x0.z, x0.w, x1.x, x1.y, x1.z, x1.w};

    float h[C_], hn[C_];
#pragma unroll
    for (int o = 0; o < C_; o++) {
        float a = b_in[o];
#pragma unroll
        for (int j = 0; j < 8; j++) a = fmaf(xv[j], w_in[o * 8 + j], a);
        h[o] = fmaxf(a, 0.0f);
    }
#pragma unroll 1
    for (int L = 0; L < 10; L++) {
        const float* W = W32 + L * C_ * C_;
        const float* bb = B32 + L * C_;
#pragma unroll
        for (int o = 0; o < C_; o++) {
            float a = bb[o];
#pragma unroll
            for (int j = 0; j < C_; j++) a = fmaf(h[j], W[o * C_ + j], a);
            hn[o] = fmaxf(a, 0.0f);
        }
#pragma unroll
        for (int o = 0; o < C_; o++) h[o] = hn[o];
    }
    // gi1: gates 32..95 only (r-gate is dead). Fold bih+bhh.
    uint4* dst = (uint4*)(gi1 + (size_t)row * 64);
#pragma unroll
    for (int k = 0; k < 8; k++) {
        uint32 wbuf[4];
#pragma unroll
        for (int p = 0; p < 4; p++) {
            int o0 = k * 8 + p * 2;
            float a0 = bih1[32 + o0] + bhh1[32 + o0];
            float a1 = bih1[33 + o0] + bhh1[33 + o0];
#pragma unroll
            for (int j = 0; j < C_; j++) {
                a0 = fmaf(h[j], wih1[(32 + o0) * C_ + j], a0);
                a1 = fmaf(h[j], wih1[(33 + o0) * C_ + j], a1);
            }
            wbuf[p] = f2bf_bits(a0) | (f2bf_bits(a1) << 16);
        }
        dst[k] = make_uint4(wbuf[0], wbuf[1], wbuf[2], wbuf[3]);
    }
}

// ---------------------------------------------------------------------------
// GRU scan: one wave per sequence. Lanes 0-31 compute z-gates, lanes 32-63
// compute n-gates. Per-step structure (lessons from r7 regression):
//  - gbuf prefetch is RAW ushort; bf2f at use (load never waited on)
//  - dot reads hs[32] SGPRs; 8 fma chains of depth 4 (ILP)
//  - permlane32_swap half-broadcast (no LDS)
//  - 32-readlane refresh block at END of step (no SGPR-write hazard)
// ---------------------------------------------------------------------------
__global__ __launch_bounds__(64) void kGru(
    const ushort16* __restrict__ gi_f, const ushort16* __restrict__ gi_r,
    const float* __restrict__ whh_f, const float* __restrict__ whh_r,
    ushort16* __restrict__ out, int outStride, int col_f, int col_r)
{
    const int blk = blockIdx.x;
    const bool rev = blk >= 64;
    const int b = blk & 63;
    const int lane = threadIdx.x;
    const bool isZ = lane < 32;

    const ushort16* gi = rev ? gi_r : gi_f;
    const float* whh = rev ? whh_r : whh_f;
    const int colbase = rev ? col_r : col_f;

    // z: sigmoid(x) = rcp(1+2^(-x*log2e));  n: tanh(x) = 2*rcp(1+2^(-2x*log2e))-1
    const float cs = isZ ? -1.442695040889f : -2.885390081777f;
    const float cm = isZ ? 1.0f : 2.0f;
    const float ca = isZ ? 0.0f : -1.0f;

    // recurrent weights for this lane's gate (raw, unscaled)
    float w[32];
    const float4* wr = (const float4*)(whh + (32 + lane) * 32);
#pragma unroll
    for (int k = 0; k < 8; k++) {
        float4 q = wr[k];
        w[4 * k + 0] = q.x; w[4 * k + 1] = q.y;
        w[4 * k + 2] = q.z; w[4 * k + 3] = q.w;
    }

    float hs[32];  // wave-uniform hidden state (SGPRs via readlane)
#pragma unroll
    for (int j = 0; j < 32; j++) hs[j] = 0.0f;
    float h_mine = 0.0f;  // h[lane&31], maintained in all lanes

    const ushort16* gp = gi + (size_t)b * T_ * 64 + lane;

    ushort16 gbuf[8];  // 8-deep RAW prefetch of gi (convert at use, 8 steps later)
#pragma unroll
    for (int u = 0; u < 8; u++) {
        int t = rev ? (T_ - 1 - u) : u;
        gbuf[u] = gp[(size_t)t * 64];
    }

    for (int s0 = 0; s0 < T_; s0 += 8) {
#pragma unroll
        for (int u = 0; u < 8; u++) {
            const int s = s0 + u;
            float g = bf2f(gbuf[u]);   // loaded 8 steps ago: no wait
            // prefetch step s+8 (clamped; value unused past the end) - RAW
            int sp = s + 8; if (sp > T_ - 1) sp = T_ - 1;
            int tp = rev ? (T_ - 1 - sp) : sp;
            gbuf[u] = gp[(size_t)tp * 64];

            // dot(whh_row, h): 8 independent chains of depth 4
            float a0 = fmaf(hs[0], w[0], g);
            float a1 = hs[1] * w[1];
            float a2 = hs[2] * w[2];
            float a3 = hs[3] * w[3];
            float a4 = hs[4] * w[4];
            float a5 = hs[5] * w[5];
            float a6 = hs[6] * w[6];
            float a7 = hs[7] * w[7];
#pragma unroll
            for (int j = 1; j < 4; j++) {
                a0 = fmaf(hs[8 * j + 0], w[8 * j + 0], a0);
                a1 = fmaf(hs[8 * j + 1], w[8 * j + 1], a1);
                a2 = fmaf(hs[8 * j + 2], w[8 * j + 2], a2);
                a3 = fmaf(hs[8 * j + 3], w[8 * j + 3], a3);
                a4 = fmaf(hs[8 * j + 4], w[8 * j + 4], a4);
                a5 = fmaf(hs[8 * j + 5], w[8 * j + 5], a5);
                a6 = fmaf(hs[8 * j + 6], w[8 * j + 6], a6);
                a7 = fmaf(hs[8 * j + 7], w[8 * j + 7], a7);
            }
            float b0 = a0 + a1, b1 = a2 + a3, b2 = a4 + a5, b3 = a6 + a7;
            float gs = (b0 + b1) + (b2 + b3);       // g + whh@h

            float e = __builtin_amdgcn_exp2f(gs * cs);
            float r = __builtin_amdgcn_rcpf(1.0f + e);
            float v = fmaf(cm, r, ca);              // z (lanes<32) or n (lanes>=32)

            // half-swap via VALU permlane (no LDS round-trip)
            uint32 zb, nb;
            half_swap(__float_as_uint(v), zb, nb);
            float z_ = __uint_as_float(zb);
            float n_ = __uint_as_float(nb);

            float hnv = fmaf(z_, h_mine - n_, n_);  // (1-z)*n + z*h
            h_mine = hnv;

            int t = rev ? (T_ - 1 - s) : s;
            if (lane < 32)
                out[((size_t)b * T_ + t) * outStride + colbase + lane] = (ushort16)f2bf_bits(hnv);

            // refresh wave-uniform h into SGPRs (block of independent readlanes,
            // consumed ~80 instructions later -> no SGPR-write hazard)
            uint32 hb = __float_as_uint(hnv);
#pragma unroll
            for (int j = 0; j < 32; j++)
                hs[j] = __uint_as_float(__builtin_amdgcn_readlane(hb, j));
        }
    }
}

// ---------------------------------------------------------------------------
// Kernel C: dec1-3 + gi2 forward + gi2 reverse
// ---------------------------------------------------------------------------
__global__ __launch_bounds__(256) void kC(
    const ushort16* __restrict__ ys1,
    const float* __restrict__ W32, const float* __restrict__ B32,
    const float* __restrict__ wih2, const float* __restrict__ bih2, const float* __restrict__ bhh2,
    const float* __restrict__ wih2r, const float* __restrict__ bih2r, const float* __restrict__ bhh2r,
    ushort16* __restrict__ gi2f, ushort16* __restrict__ gi2r)
{
    const int row = blockIdx.x * 256 + threadIdx.x;
    float h[C_], hn[C_];
    const uint4* src = (const uint4*)(ys1 + (size_t)row * 32);
#pragma unroll
    for (int k = 0; k < 4; k++) {
        uint4 v = src[k];
        unpack2(v.x, h[8 * k + 0], h[8 * k + 1]);
        unpack2(v.y, h[8 * k + 2], h[8 * k + 3]);
        unpack2(v.z, h[8 * k + 4], h[8 * k + 5]);
        unpack2(v.w, h[8 * k + 6], h[8 * k + 7]);
    }
#pragma unroll 1
    for (int L = 10; L < 13; L++) {
        const float* W = W32 + L * C_ * C_;
        const float* bb = B32 + L * C_;
#pragma unroll
        for (int o = 0; o < C_; o++) {
            float a = bb[o];
#pragma unroll
            for (int j = 0; j < C_; j++) a = fmaf(h[j], W[o * C_ + j], a);
            hn[o] = fmaxf(a, 0.0f);
        }
#pragma unroll
        for (int o = 0; o < C_; o++) h[o] = hn[o];
    }
#pragma unroll 1
    for (int d = 0; d < 2; d++) {
        const float* wih = d ? wih2r : wih2;
        const float* bi = d ? bih2r : bih2;
        const float* bh = d ? bhh2r : bhh2;
        uint4* dst = (uint4*)((d ? gi2r : gi2f) + (size_t)row * 64);
#pragma unroll
        for (int k = 0; k < 8; k++) {
            uint32 wbuf[4];
#pragma unroll
            for (int p = 0; p < 4; p++) {
                int o0 = k * 8 + p * 2;
                float a0 = bi[32 + o0] + bh[32 + o0];
                float a1 = bi[33 + o0] + bh[33 + o0];
#pragma unroll
                for (int j = 0; j < C_; j++) {
                    a0 = fmaf(h[j], wih[(32 + o0) * C_ + j], a0);
                    a1 = fmaf(h[j], wih[(33 + o0) * C_ + j], a1);
                }
                wbuf[p] = f2bf_bits(a0) | (f2bf_bits(a1) << 16);
            }
            dst[k] = make_uint4(wbuf[0], wbuf[1], wbuf[2], wbuf[3]);
        }
    }
}

// ---------------------------------------------------------------------------
// Kernel E: up1 (64->32) + up2-5 + out head + sigmoid
// ---------------------------------------------------------------------------
__global__ __launch_bounds__(256) void kE(
    const ushort16* __restrict__ hcat,
    const float* __restrict__ w_up1, const float* __restrict__ b_up1,
    const float* __restrict__ W32, const float* __restrict__ B32,
    const float* __restrict__ w_out, const float* __restrict__ b_out,
    float* __restrict__ outp)
{
    const int row = blockIdx.x * 256 + threadIdx.x;
    float h64[64];
    const uint4* src = (const uint4*)(hcat + (size_t)row * 64);
#pragma unroll
    for (int k = 0; k < 8; k++) {
        uint4 v = src[k];
        unpack2(v.x, h64[8 * k + 0], h64[8 * k + 1]);
        unpack2(v.y, h64[8 * k + 2], h64[8 * k + 3]);
        unpack2(v.z, h64[8 * k + 4], h64[8 * k + 5]);
        unpack2(v.w, h64[8 * k + 6], h64[8 * k + 7]);
    }
    float h[C_], hn[C_];
#pragma unroll
    for (int o = 0; o < C_; o++) {
        float a = b_up1[o];
#pragma unroll
        for (int j = 0; j < 64; j++) a = fmaf(h64[j], w_up1[o * 64 + j], a);
        h[o] = fmaxf(a, 0.0f);
    }
#pragma unroll 1
    for (int L = 13; L < 17; L++) {
        const float* W = W32 + L * C_ * C_;
        const float* bb = B32 + L * C_;
#pragma unroll
        for (int o = 0; o < C_; o++) {
            float a = bb[o];
#pragma unroll
            for (int j = 0; j < C_; j++) a = fmaf(h[j], W[o * C_ + j], a);
            hn[o] = fmaxf(a, 0.0f);
        }
#pragma unroll
        for (int o = 0; o < C_; o++) h[o] = hn[o];
    }
    float r0 = b_out[0], r1 = b_out[1];
#pragma unroll
    for (int j = 0; j < C_; j++) {
        r0 = fmaf(h[j], w_out[j], r0);
        r1 = fmaf(h[j], w_out[32 + j], r1);
    }
    float2 res = make_float2(fast_sigmoid(r0), fast_sigmoid(r1));
    ((float2*)outp)[row] = res;
}

// ---------------------------------------------------------------------------
extern "C" void kernel_launch(void* const* d_in, const int* in_sizes, int n_in,
                              void* d_out, int out_size, void* d_ws, size_t ws_size,
                              hipStream_t stream) {
    const float* x     = (const float*)d_in[0];
    const float* w_in  = (const float*)d_in[1];
    const float* b_in  = (const float*)d_in[2];
    const float* W32   = (const float*)d_in[3];
    const float* B32   = (const float*)d_in[4];
    const float* w_up1 = (const float*)d_in[5];
    const float* b_up1 = (const float*)d_in[6];
    const float* w_out = (const float*)d_in[7];
    const float* b_out = (const float*)d_in[8];
    const float* wih1  = (const float*)d_in[9];
    const float* whh1  = (const float*)d_in[10];
    const float* bih1  = (const float*)d_in[11];
    const float* bhh1  = (const float*)d_in[12];
    const float* wih2  = (const float*)d_in[13];
    const float* whh2  = (const float*)d_in[14];
    const float* bih2  = (const float*)d_in[15];
    const float* bhh2  = (const float*)d_in[16];
    const float* wih2r = (const float*)d_in[17];
    const float* whh2r = (const float*)d_in[18];
    const float* bih2r = (const float*)d_in[19];
    const float* bhh2r = (const float*)d_in[20];

    const size_t NB = (size_t)B_ * T_;  // 262144 rows
    // Workspace layout (112 MB): gi2f aliases gi1 (dead after gru1).
    ushort16* gi1  = (ushort16*)d_ws;        // [NB][64] bf16 : 32 MB
    ushort16* gi2f = gi1;                    // aliases gi1
    ushort16* gi2r = gi1  + NB * 64;         // 32 MB
    ushort16* ys1  = gi2r + NB * 64;         // [NB][32] bf16 : 16 MB
    ushort16* hcat = ys1  + NB * 32;         // [NB][64] bf16 : 32 MB

    const int rowBlocks = (int)(NB / 256);   // 1024

    kA<<<rowBlocks, 256, 0, stream>>>(x, w_in, b_in, W32, B32, wih1, bih1, bhh1, gi1);
    kGru<<<64, 64, 0, stream>>>(gi1, gi1, whh1, whh1, ys1, 32, 0, 0);
    kC<<<rowBlocks, 256, 0, stream>>>(ys1, W32, B32, wih2, bih2, bhh2,
                                      wih2r, bih2r, bhh2r, gi2f, gi2r);
    kGru<<<128, 64, 0, stream>>>(gi2f, gi2r, whh2, whh2r, hcat, 64, 0, 32);
    kE<<<rowBlocks, 256, 0, stream>>>(hcat, w_up1, b_up1, W32, B32, w_out, b_out,
                                      (float*)d_out);
}

// Round 11
// 1791.466 us; speedup vs baseline: 1.7191x; 1.2316x over previous
//
#include <hip/hip_runtime.h>
#include <stdint.h>

#define B_ 64
#define T_ 4096
#define C_ 32

typedef unsigned int uint32;
typedef unsigned short ushort16;
typedef unsigned int uint32x2 __attribute__((ext_vector_type(2)));
typedef _Float16 half2v __attribute__((ext_vector_type(2)));

__device__ __forceinline__ float bf2f(ushort16 u) {
    return __uint_as_float(((uint32)u) << 16);
}
__device__ __forceinline__ uint32 f2bf_bits(float f) {  // round-to-nearest-even bf16
    uint32 u = __float_as_uint(f);
    uint32 r = u + 0x7fffu + ((u >> 16) & 1u);
    return r >> 16;
}
__device__ __forceinline__ void unpack2(uint32 u, float& f0, float& f1) {
    f0 = __uint_as_float(u << 16);
    f1 = __uint_as_float(u & 0xffff0000u);
}
__device__ __forceinline__ float fast_sigmoid(float x) {
    float e = __builtin_amdgcn_exp2f(x * -1.442695040889f);
    return __builtin_amdgcn_rcpf(1.0f + e);
}
// cvt_pkrtz returns __fp16x2; bit-cast to _Float16x2 for fdot2
__device__ __forceinline__ half2v pkrtz(float a, float b) {
    return __builtin_bit_cast(half2v, __builtin_amdgcn_cvt_pkrtz(a, b));
}

// half-swap across the two 32-lane halves; given v = z in lanes 0-31, n in
// lanes 32-63, returns (z broadcast to all lanes, n broadcast to all lanes).
// Verified on HW in rounds 7/8 (passed, absmax 0.0).
__device__ __forceinline__ void half_swap(uint32 vb, uint32& zb, uint32& nb) {
#if __has_builtin(__builtin_amdgcn_permlane32_swap)
    uint32x2 sw = __builtin_amdgcn_permlane32_swap(vb, vb, false, false);
    zb = sw.x; nb = sw.y;
#else
    uint32 a = vb, b = vb;
    asm("v_permlane32_swap_b32 %0, %1" : "+v"(a), "+v"(b));
    zb = a; nb = b;
#endif
}

#if __has_builtin(__builtin_amdgcn_fdot2)
#define HAVE_DOT2 1
#else
#define HAVE_DOT2 0
#endif

// ---------------------------------------------------------------------------
// Kernel A: conv_in + down1-5 + feat1-5 + gi1 (input gates for gru1, bf16)
// ---------------------------------------------------------------------------
__global__ __launch_bounds__(256) void kA(
    const float* __restrict__ x, const float* __restrict__ w_in, const float* __restrict__ b_in,
    const float* __restrict__ W32, const float* __restrict__ B32,
    const float* __restrict__ wih1, const float* __restrict__ bih1, const float* __restrict__ bhh1,
    ushort16* __restrict__ gi1)
{
    const int row = blockIdx.x * 256 + threadIdx.x;  // 0 .. B*T-1
    const float4* xr = (const float4*)(x + (size_t)row * 8);
    float4 x0 = xr[0], x1 = xr[1];
    float xv[8] = {x0.x, x0.y, x0.z, x0.w, x1.x, x1.y, x1.z, x1.w};

    float h[C_], hn[C_];
#pragma unroll
    for (int o = 0; o < C_; o++) {
        float a = b_in[o];
#pragma unroll
        for (int j = 0; j < 8; j++) a = fmaf(xv[j], w_in[o * 8 + j], a);
        h[o] = fmaxf(a, 0.0f);
    }
#pragma unroll 1
    for (int L = 0; L < 10; L++) {
        const float* W = W32 + L * C_ * C_;
        const float* bb = B32 + L * C_;
#pragma unroll
        for (int o = 0; o < C_; o++) {
            float a = bb[o];
#pragma unroll
            for (int j = 0; j < C_; j++) a = fmaf(h[j], W[o * C_ + j], a);
            hn[o] = fmaxf(a, 0.0f);
        }
#pragma unroll
        for (int o = 0; o < C_; o++) h[o] = hn[o];
    }
    // gi1: gates 32..95 only (r-gate is dead). Fold bih+bhh.
    uint4* dst = (uint4*)(gi1 + (size_t)row * 64);
#pragma unroll
    for (int k = 0; k < 8; k++) {
        uint32 wbuf[4];
#pragma unroll
        for (int p = 0; p < 4; p++) {
            int o0 = k * 8 + p * 2;
            float a0 = bih1[32 + o0] + bhh1[32 + o0];
            float a1 = bih1[33 + o0] + bhh1[33 + o0];
#pragma unroll
            for (int j = 0; j < C_; j++) {
                a0 = fmaf(h[j], wih1[(32 + o0) * C_ + j], a0);
                a1 = fmaf(h[j], wih1[(33 + o0) * C_ + j], a1);
            }
            wbuf[p] = f2bf_bits(a0) | (f2bf_bits(a1) << 16);
        }
        dst[k] = make_uint4(wbuf[0], wbuf[1], wbuf[2], wbuf[3]);
    }
}

// ---------------------------------------------------------------------------
// GRU scan: one wave per sequence. Lanes 0-31 compute z-gates, lanes 32-63
// compute n-gates. Per-step structure:
//  - gbuf prefetch RAW ushort; bf2f at use (8 steps later; no wait)
//  - dot via 16x v_dot2_f32_f16 (4 chains), h broadcast as 16 packed-f16 SGPRs
//    built from 1 DPP + 1 cvt_pkrtz + 16 readlanes at END of step
//  - permlane32_swap half-broadcast (no LDS)
//  - __launch_bounds__(64,1): full VGPR file; keeps w/gbuf out of AGPRs
// ---------------------------------------------------------------------------
__global__ __launch_bounds__(64, 1) void kGru(
    const ushort16* __restrict__ gi_f, const ushort16* __restrict__ gi_r,
    const float* __restrict__ whh_f, const float* __restrict__ whh_r,
    ushort16* __restrict__ out, int outStride, int col_f, int col_r)
{
    const int blk = blockIdx.x;
    const bool rev = blk >= 64;
    const int b = blk & 63;
    const int lane = threadIdx.x;
    const bool isZ = lane < 32;

    const ushort16* gi = rev ? gi_r : gi_f;
    const float* whh = rev ? whh_r : whh_f;
    const int colbase = rev ? col_r : col_f;

    // z: sigmoid(x) = rcp(1+2^(-x*log2e));  n: tanh(x) = 2*rcp(1+2^(-2x*log2e))-1
    const float cs = isZ ? -1.442695040889f : -2.885390081777f;
    const float cm = isZ ? 1.0f : 2.0f;
    const float ca = isZ ? 0.0f : -1.0f;

    const float4* wr = (const float4*)(whh + (32 + lane) * 32);

#if HAVE_DOT2
    // recurrent weights packed as f16 pairs (w[2j], w[2j+1])
    half2v wpk[16];
#pragma unroll
    for (int k = 0; k < 8; k++) {
        float4 q = wr[k];
        wpk[2 * k]     = pkrtz(q.x, q.y);
        wpk[2 * k + 1] = pkrtz(q.z, q.w);
    }
    uint32 hp[16];  // packed f16 pairs of h, wave-uniform (SGPRs)
#pragma unroll
    for (int j = 0; j < 16; j++) hp[j] = 0;
#else
    float w[32];
#pragma unroll
    for (int k = 0; k < 8; k++) {
        float4 q = wr[k];
        w[4 * k + 0] = q.x; w[4 * k + 1] = q.y;
        w[4 * k + 2] = q.z; w[4 * k + 3] = q.w;
    }
    float hs[32];
#pragma unroll
    for (int j = 0; j < 32; j++) hs[j] = 0.0f;
#endif

    float h_mine = 0.0f;  // h[lane&31], maintained in all lanes

    const ushort16* gp = gi + (size_t)b * T_ * 64 + lane;

    ushort16 gbuf[8];  // 8-deep RAW prefetch of gi (convert at use, 8 steps later)
#pragma unroll
    for (int u = 0; u < 8; u++) {
        int t = rev ? (T_ - 1 - u) : u;
        gbuf[u] = gp[(size_t)t * 64];
    }

    for (int s0 = 0; s0 < T_; s0 += 8) {
#pragma unroll
        for (int u = 0; u < 8; u++) {
            const int s = s0 + u;
            float g = bf2f(gbuf[u]);   // loaded 8 steps ago: no wait
            // prefetch step s+8 (clamped; value unused past the end) - RAW
            int sp = s + 8; if (sp > T_ - 1) sp = T_ - 1;
            int tp = rev ? (T_ - 1 - sp) : sp;
            gbuf[u] = gp[(size_t)tp * 64];

#if HAVE_DOT2
            // dot(whh_row, h): 16 dot2 in 4 independent chains
            float a0 = g, a1 = 0.f, a2 = 0.f, a3 = 0.f;
#pragma unroll
            for (int j = 0; j < 4; j++) {
                a0 = __builtin_amdgcn_fdot2(wpk[j],      __builtin_bit_cast(half2v, hp[j]),      a0, false);
                a1 = __builtin_amdgcn_fdot2(wpk[j + 4],  __builtin_bit_cast(half2v, hp[j + 4]),  a1, false);
                a2 = __builtin_amdgcn_fdot2(wpk[j + 8],  __builtin_bit_cast(half2v, hp[j + 8]),  a2, false);
                a3 = __builtin_amdgcn_fdot2(wpk[j + 12], __builtin_bit_cast(half2v, hp[j + 12]), a3, false);
            }
#else
            float a0 = fmaf(hs[0], w[0], g);
            float a1 = hs[1] * w[1];
            float a2 = hs[2] * w[2];
            float a3 = hs[3] * w[3];
            float a4 = hs[4] * w[4];
            float a5 = hs[5] * w[5];
            float a6 = hs[6] * w[6];
            float a7 = hs[7] * w[7];
#pragma unroll
            for (int j = 1; j < 4; j++) {
                a0 = fmaf(hs[8 * j + 0], w[8 * j + 0], a0);
                a1 = fmaf(hs[8 * j + 1], w[8 * j + 1], a1);
                a2 = fmaf(hs[8 * j + 2], w[8 * j + 2], a2);
                a3 = fmaf(hs[8 * j + 3], w[8 * j + 3], a3);
                a4 = fmaf(hs[8 * j + 4], w[8 * j + 4], a4);
                a5 = fmaf(hs[8 * j + 5], w[8 * j + 5], a5);
                a6 = fmaf(hs[8 * j + 6], w[8 * j + 6], a6);
                a7 = fmaf(hs[8 * j + 7], w[8 * j + 7], a7);
            }
            a0 = (a0 + a4); a1 = (a1 + a5); a2 = (a2 + a6); a3 = (a3 + a7);
#endif
            float gs = (a0 + a1) + (a2 + a3);       // g + whh@h

            float e = __builtin_amdgcn_exp2f(gs * cs);
            float r = __builtin_amdgcn_rcpf(1.0f + e);
            float v = fmaf(cm, r, ca);              // z (lanes<32) or n (lanes>=32)

            // half-swap via VALU permlane (no LDS round-trip)
            uint32 zb, nb;
            half_swap(__float_as_uint(v), zb, nb);
            float z_ = __uint_as_float(zb);
            float n_ = __uint_as_float(nb);

            float hnv = fmaf(z_, h_mine - n_, n_);  // (1-z)*n + z*h
            h_mine = hnv;

            int t = rev ? (T_ - 1 - s) : s;
            if (lane < 32)
                out[((size_t)b * T_ + t) * outStride + colbase + lane] = (ushort16)f2bf_bits(hnv);

            // broadcast h for the next step (consumed ~1 step later: no hazard)
#if HAVE_DOT2
            // neighbor (lane^1) via DPP quad_perm [1,0,3,2]; pack (h_even, h_odd)
            uint32 hbv = __float_as_uint(hnv);
            uint32 nbv = (uint32)__builtin_amdgcn_mov_dpp((int)hbv, 0xB1, 0xF, 0xF, true);
            half2v pkh = pkrtz(hnv, __uint_as_float(nbv));
            uint32 pk = __builtin_bit_cast(uint32, pkh);
#pragma unroll
            for (int j = 0; j < 16; j++)
                hp[j] = (uint32)__builtin_amdgcn_readlane(pk, 2 * j);
#else
            uint32 hb = __float_as_uint(hnv);
#pragma unroll
            for (int j = 0; j < 32; j++)
                hs[j] = __uint_as_float(__builtin_amdgcn_readlane(hb, j));
#endif
        }
    }
}

// ---------------------------------------------------------------------------
// Kernel C: dec1-3 + gi2 forward + gi2 reverse
// ---------------------------------------------------------------------------
__global__ __launch_bounds__(256) void kC(
    const ushort16* __restrict__ ys1,
    const float* __restrict__ W32, const float* __restrict__ B32,
    const float* __restrict__ wih2, const float* __restrict__ bih2, const float* __restrict__ bhh2,
    const float* __restrict__ wih2r, const float* __restrict__ bih2r, const float* __restrict__ bhh2r,
    ushort16* __restrict__ gi2f, ushort16* __restrict__ gi2r)
{
    const int row = blockIdx.x * 256 + threadIdx.x;
    float h[C_], hn[C_];
    const uint4* src = (const uint4*)(ys1 + (size_t)row * 32);
#pragma unroll
    for (int k = 0; k < 4; k++) {
        uint4 v = src[k];
        unpack2(v.x, h[8 * k + 0], h[8 * k + 1]);
        unpack2(v.y, h[8 * k + 2], h[8 * k + 3]);
        unpack2(v.z, h[8 * k + 4], h[8 * k + 5]);
        unpack2(v.w, h[8 * k + 6], h[8 * k + 7]);
    }
#pragma unroll 1
    for (int L = 10; L < 13; L++) {
        const float* W = W32 + L * C_ * C_;
        const float* bb = B32 + L * C_;
#pragma unroll
    for (int o = 0; o < C_; o++) {
            float a = bb[o];
#pragma unroll
            for (int j = 0; j < C_; j++) a = fmaf(h[j], W[o * C_ + j], a);
            hn[o] = fmaxf(a, 0.0f);
        }
#pragma unroll
        for (int o = 0; o < C_; o++) h[o] = hn[o];
    }
#pragma unroll 1
    for (int d = 0; d < 2; d++) {
        const float* wih = d ? wih2r : wih2;
        const float* bi = d ? bih2r : bih2;
        const float* bh = d ? bhh2r : bhh2;
        uint4* dst = (uint4*)((d ? gi2r : gi2f) + (size_t)row * 64);
#pragma unroll
        for (int k = 0; k < 8; k++) {
            uint32 wbuf[4];
#pragma unroll
            for (int p = 0; p < 4; p++) {
                int o0 = k * 8 + p * 2;
                float a0 = bi[32 + o0] + bh[32 + o0];
                float a1 = bi[33 + o0] + bh[33 + o0];
#pragma unroll
                for (int j = 0; j < C_; j++) {
                    a0 = fmaf(h[j], wih[(32 + o0) * C_ + j], a0);
                    a1 = fmaf(h[j], wih[(33 + o0) * C_ + j], a1);
                }
                wbuf[p] = f2bf_bits(a0) | (f2bf_bits(a1) << 16);
            }
            dst[k] = make_uint4(wbuf[0], wbuf[1], wbuf[2], wbuf[3]);
        }
    }
}

// ---------------------------------------------------------------------------
// Kernel E: up1 (64->32) + up2-5 + out head + sigmoid
// ---------------------------------------------------------------------------
__global__ __launch_bounds__(256) void kE(
    const ushort16* __restrict__ hcat,
    const float* __restrict__ w_up1, const float* __restrict__ b_up1,
    const float* __restrict__ W32, const float* __restrict__ B32,
    const float* __restrict__ w_out, const float* __restrict__ b_out,
    float* __restrict__ outp)
{
    const int row = blockIdx.x * 256 + threadIdx.x;
    float h64[64];
    const uint4* src = (const uint4*)(hcat + (size_t)row * 64);
#pragma unroll
    for (int k = 0; k < 8; k++) {
        uint4 v = src[k];
        unpack2(v.x, h64[8 * k + 0], h64[8 * k + 1]);
        unpack2(v.y, h64[8 * k + 2], h64[8 * k + 3]);
        unpack2(v.z, h64[8 * k + 4], h64[8 * k + 5]);
        unpack2(v.w, h64[8 * k + 6], h64[8 * k + 7]);
    }
    float h[C_], hn[C_];
#pragma unroll
    for (int o = 0; o < C_; o++) {
        float a = b_up1[o];
#pragma unroll
        for (int j = 0; j < 64; j++) a = fmaf(h64[j], w_up1[o * 64 + j], a);
        h[o] = fmaxf(a, 0.0f);
    }
#pragma unroll 1
    for (int L = 13; L < 17; L++) {
        const float* W = W32 + L * C_ * C_;
        const float* bb = B32 + L * C_;
#pragma unroll
        for (int o = 0; o < C_; o++) {
            float a = bb[o];
#pragma unroll
            for (int j = 0; j < C_; j++) a = fmaf(h[j], W[o * C_ + j], a);
            hn[o] = fmaxf(a, 0.0f);
        }
#pragma unroll
        for (int o = 0; o < C_; o++) h[o] = hn[o];
    }
    float r0 = b_out[0], r1 = b_out[1];
#pragma unroll
    for (int j = 0; j < C_; j++) {
        r0 = fmaf(h[j], w_out[j], r0);
        r1 = fmaf(h[j], w_out[32 + j], r1);
    }
    float2 res = make_float2(fast_sigmoid(r0), fast_sigmoid(r1));
    ((float2*)outp)[row] = res;
}

// ---------------------------------------------------------------------------
extern "C" void kernel_launch(void* const* d_in, const int* in_sizes, int n_in,
                              void* d_out, int out_size, void* d_ws, size_t ws_size,
                              hipStream_t stream) {
    const float* x     = (const float*)d_in[0];
    const float* w_in  = (const float*)d_in[1];
    const float* b_in  = (const float*)d_in[2];
    const float* W32   = (const float*)d_in[3];
    const float* B32   = (const float*)d_in[4];
    const float* w_up1 = (const float*)d_in[5];
    const float* b_up1 = (const float*)d_in[6];
    const float* w_out = (const float*)d_in[7];
    const float* b_out = (const float*)d_in[8];
    const float* wih1  = (const float*)d_in[9];
    const float* whh1  = (const float*)d_in[10];
    const float* bih1  = (const float*)d_in[11];
    const float* bhh1  = (const float*)d_in[12];
    const float* wih2  = (const float*)d_in[13];
    const float* whh2  = (const float*)d_in[14];
    const float* bih2  = (const float*)d_in[15];
    const float* bhh2  = (const float*)d_in[16];
    const float* wih2r = (const float*)d_in[17];
    const float* whh2r = (const float*)d_in[18];
    const float* bih2r = (const float*)d_in[19];
    const float* bhh2r = (const float*)d_in[20];

    const size_t NB = (size_t)B_ * T_;  // 262144 rows
    // Workspace layout (112 MB): gi2f aliases gi1 (dead after gru1).
    ushort16* gi1  = (ushort16*)d_ws;        // [NB][64] bf16 : 32 MB
    ushort16* gi2f = gi1;                    // aliases gi1
    ushort16* gi2r = gi1  + NB * 64;         // 32 MB
    ushort16* ys1  = gi2r + NB * 64;         // [NB][32] bf16 : 16 MB
    ushort16* hcat = ys1  + NB * 32;         // [NB][64] bf16 : 32 MB

    const int rowBlocks = (int)(NB / 256);   // 1024

    kA<<<rowBlocks, 256, 0, stream>>>(x, w_in, b_in, W32, B32, wih1, bih1, bhh1, gi1);
    kGru<<<64, 64, 0, stream>>>(gi1, gi1, whh1, whh1, ys1, 32, 0, 0);
    kC<<<rowBlocks, 256, 0, stream>>>(ys1, W32, B32, wih2, bih2, bhh2,
                                      wih2r, bih2r, bhh2r, gi2f, gi2r);
    kGru<<<128, 64, 0, stream>>>(gi2f, gi2r, whh2, whh2r, hcat, 64, 0, 32);
    kE<<<rowBlocks, 256, 0, stream>>>(hcat, w_up1, b_up1, W32, B32, w_out, b_out,
                                      (float*)d_out);
}